// Round 14
// baseline (110.994 us; speedup 1.0000x reference)
//
#include <hip/hip_runtime.h>

// Problem constants (fixed by the reference)
#define BATCH   32
#define C_OUT_N 128
#define NK      5
#define C_IN_N  (NK * C_OUT_N)   // 640
#define HIN     58
#define WIN     58
#define HOUT    56
#define WOUT    56
#define NPIX    (HOUT * WOUT)                       // 3136
#define NTILE   (HOUT * (WOUT / 8))                 // 392 8-px tiles
#define OUT_PLANE ((size_t)BATCH * C_OUT_N * NPIX)  // 12,845,056

// Shift set fixed: REAL_PAD[t] = 4 - 3*t -> {4,1,-2,-5,-8}
// LDS tile: f16 [NK*HIN][70]; x col c at idx 7+c; zeros at idx 0..6, 65..69.
// Window for 8-px tile (h,w0): idx (h+1)*70 + w0 + [0..19]; px i tap t reads
// window col i + 12 - 3t. All reads are b32 f16-pairs (stride 70 = 35 dwords,
// odd -> rows spread across all 32 banks; R10-measured best structure).
// LDS = 290*70*2 + 16 B zero scratch = 40,616 B -> 4 blocks/CU, 512 thr.
#define NTHREADS   512
#define LDS_STRIDE 70                        // f16 elements
#define LDS_ROWS   (NK * HIN)                // 290
#define CH_STRIDE  (HIN * LDS_STRIDE)        // 4060
#define ZOFF       (LDS_ROWS * LDS_STRIDE)   // 20,300: 8-ushort zero scratch
#define LDS_HALVES (ZOFF + 8)                // 20,308 -> 40,616 B
#define NV4        (NK * HIN * WIN / 4)      // 4205 float4s per (b,co) chunk

typedef _Float16 h2 __attribute__((ext_vector_type(2)));

static __device__ __forceinline__ unsigned int h2u(h2 v) {
    unsigned int r; __builtin_memcpy(&r, &v, 4); return r;
}
static __device__ __forceinline__ h2 uh2(unsigned int u) {
    h2 r; __builtin_memcpy(&r, &u, 4); return r;
}
// shifted-by-one-column f16 pair via v_alignbit_b32
static __device__ __forceinline__ h2 algn(h2 lo, h2 hi) {
    return uh2(__builtin_amdgcn_alignbit(h2u(hi), h2u(lo), 16));
}
// packed f32x2 -> f16x2 (round-toward-zero), bit-cast to our h2 type
static __device__ __forceinline__ h2 pkrtz(float a, float b) {
    auto t = __builtin_amdgcn_cvt_pkrtz(a, b);   // __fp16 ext_vector(2)
    h2 r; __builtin_memcpy(&r, &t, 4); return r;
}
// f16(n) duplicated in both 16-bit halves, n in 0..4 (scalar cselect chain)
static __device__ __forceinline__ unsigned int w16x2(unsigned int n) {
    unsigned int r = 0u;
    r = (n == 1) ? 0x3C003C00u : r;
    r = (n == 2) ? 0x40004000u : r;
    r = (n == 3) ? 0x42004200u : r;
    r = (n == 4) ? 0x44004400u : r;
    return r;
}

__global__ __launch_bounds__(NTHREADS, 8) void addshift_sw_kernel(
    const float* __restrict__ x,          // (B, C_IN, 58, 58)
    const int*   __restrict__ pad_hv,     // (C_IN, 8): [0..3]=h shifts, [4..7]=v shifts
    const int*   __restrict__ idx_id,     // (C_OUT, 4), values in [co*5, co*5+5)
    float*       __restrict__ out)        // out_h | out_v | out_id concatenated
{
    extern __shared__ _Float16 lds[];

    const int bc  = blockIdx.x;           // b * C_OUT + co
    const int b   = bc / C_OUT_N;
    const int co  = bc - b * C_OUT_N;
    const int tid = threadIdx.x;

    // ---- zero column margins (12/row) + the 8-ushort zero scratch
    for (int i = tid; i < LDS_ROWS * 12 + 8; i += NTHREADS) {
        int idx;
        if (i < LDS_ROWS * 12) {
            int j = i / 12;
            int m = i - j * 12;
            int c = (m < 7) ? m : (58 + m);   // 0..6 and 65..69
            idx = j * LDS_STRIDE + c;
        } else {
            idx = ZOFF + (i - LDS_ROWS * 12);
        }
        lds[idx] = (_Float16)0.f;
    }

    // ---- stage 5-channel chunk: float4 global loads -> f16 LDS
    const float* xbase = x + (size_t)(b * C_IN_N + co * NK) * (HIN * WIN);
    for (int i = tid; i < NV4; i += NTHREADS) {
        int g = 4 * i;
        float4 v = *(const float4*)(xbase + g);
        int r = g / 58;                   // const division -> magic mul
        int c = g - r * 58;               // even, 0..56
        _Float16* dst = &lds[r * LDS_STRIDE + 7 + c];
        if (c <= 54) {
            dst[0] = (_Float16)v.x;
            *(h2*)(dst + 1) = pkrtz(v.y, v.z);   // even idx, b32 write
            dst[3] = (_Float16)v.w;
        } else {                          // c == 56: last 2 floats wrap to next row
            dst[0] = (_Float16)v.x;
            dst[1] = (_Float16)v.y;
            _Float16* d2 = &lds[(r + 1) * LDS_STRIDE + 7];
            d2[0] = (_Float16)v.z;
            d2[1] = (_Float16)v.w;
        }
    }

    // ---- block-uniform weights, built in SCALAR integer math:
    // nibble-packed slot counts (slot = (4 - shift)/3), then count -> f16x2 bits
    unsigned int swh[NK][5], swv[NK][5], swc[NK];
    {
        unsigned int ccnt = 0;
        #pragma unroll
        for (int g = 0; g < 4; ++g)
            ccnt += 1u << (4 * (idx_id[co * 4 + g] - co * NK));
        #pragma unroll
        for (int k = 0; k < NK; ++k) {
            unsigned int hc = 0, vc = 0;
            #pragma unroll
            for (int g = 0; g < 4; ++g) {
                int sh_v = pad_hv[(co * NK + k) * 8 + g];       // {4,1,-2,-5,-8}
                int sv_v = pad_hv[(co * NK + k) * 8 + 4 + g];
                hc += 1u << (4 * ((4 - sh_v) / 3));
                vc += 1u << (4 * ((4 - sv_v) / 3));
            }
            #pragma unroll
            for (int t = 0; t < 5; ++t) {
                swh[k][t] = __builtin_amdgcn_readfirstlane(w16x2((hc >> (4 * t)) & 0xFu));
                swv[k][t] = __builtin_amdgcn_readfirstlane(w16x2((vc >> (4 * t)) & 0xFu));
            }
            swc[k] = __builtin_amdgcn_readfirstlane(w16x2((ccnt >> (4 * k)) & 0xFu));
        }
    }

    __syncthreads();

    // ---- compute: one 8-px tile per thread (392 active), b32 pairs + pk-FMA
    const int q = tid;
    if (q < NTILE) {
        const int h  = q / 7;
        const int w0 = 8 * (q - h * 7);

        // v-tap rows: clamp address in-bounds; invalid taps get weight 0
        int  voff[5];
        bool okv[5];
        #pragma unroll
        for (int t = 0; t < 5; ++t) {
            int rr = h + 5 - 3 * t;       // h+1+(4-3t)
            okv[t] = (unsigned)rr < 58u;
            int rc = rr < 0 ? 0 : (rr > 57 ? 57 : rr);
            voff[t] = rc * LDS_STRIDE + w0 + 8;
        }
        const int rowbase = (h + 1) * LDS_STRIDE + w0;

        h2 sh[4], sv[4], si[4];
        #pragma unroll
        for (int m = 0; m < 4; ++m) {
            sh[m] = h2{(_Float16)0.f, (_Float16)0.f};
            sv[m] = sh[m]; si[m] = sh[m];
        }

        #pragma unroll
        for (int k = 0; k < NK; ++k) {
            const _Float16* chp  = lds + k * CH_STRIDE;
            const _Float16* rowp = chp + rowbase;

            // 20-col window as 10 f16-pairs (b32 loads, 4B-aligned)
            h2 H[10];
            #pragma unroll
            for (int m = 0; m < 10; ++m) H[m] = *(const h2*)(rowp + 2 * m);

            // out_h: tap t -> j = 12-3t; uniform skip of zero-weight taps
            #pragma unroll
            for (int t = 0; t < 5; ++t) {
                unsigned int wb = swh[k][t];
                if (wb != 0u) {
                    h2 w2 = uh2(wb);
                    int j = 12 - 3 * t;
                    if ((j & 1) == 0) {
                        int m0 = j >> 1;
                        #pragma unroll
                        for (int m = 0; m < 4; ++m) sh[m] += w2 * H[m0 + m];
                    } else {
                        int m0 = (j - 1) >> 1;
                        #pragma unroll
                        for (int m = 0; m < 4; ++m)
                            sh[m] += w2 * algn(H[m0 + m], H[m0 + m + 1]);
                    }
                }
            }

            // out_id: center cols 8..15 = H[4..7]
            if (swc[k] != 0u) {
                h2 c2 = uh2(swc[k]);
                #pragma unroll
                for (int m = 0; m < 4; ++m) si[m] += c2 * H[4 + m];
            }

            // out_v: 4 pair-loads per nonzero tap; OOB -> weight zeroed (cndmask)
            #pragma unroll
            for (int t = 0; t < 5; ++t) {
                unsigned int wb = swv[k][t];
                if (wb != 0u) {
                    unsigned int wm = okv[t] ? wb : 0u;    // one v_cndmask
                    h2 wv2 = uh2(wm);
                    const _Float16* vp = chp + voff[t];
                    #pragma unroll
                    for (int m = 0; m < 4; ++m)
                        sv[m] += wv2 * *(const h2*)(vp + 2 * m);
                }
            }
        }

        size_t o = (size_t)bc * NPIX + h * WOUT + w0;
        *(float4*)(out + o) =
            make_float4((float)sh[0].x, (float)sh[0].y, (float)sh[1].x, (float)sh[1].y);
        *(float4*)(out + o + 4) =
            make_float4((float)sh[2].x, (float)sh[2].y, (float)sh[3].x, (float)sh[3].y);
        *(float4*)(out + OUT_PLANE + o) =
            make_float4((float)sv[0].x, (float)sv[0].y, (float)sv[1].x, (float)sv[1].y);
        *(float4*)(out + OUT_PLANE + o + 4) =
            make_float4((float)sv[2].x, (float)sv[2].y, (float)sv[3].x, (float)sv[3].y);
        *(float4*)(out + 2 * OUT_PLANE + o) =
            make_float4((float)si[0].x, (float)si[0].y, (float)si[1].x, (float)si[1].y);
        *(float4*)(out + 2 * OUT_PLANE + o + 4) =
            make_float4((float)si[2].x, (float)si[2].y, (float)si[3].x, (float)si[3].y);
    }
}

extern "C" void kernel_launch(void* const* d_in, const int* in_sizes, int n_in,
                              void* d_out, int out_size, void* d_ws, size_t ws_size,
                              hipStream_t stream) {
    const float* x      = (const float*)d_in[0];
    const int*   pad_hv = (const int*)d_in[1];
    const int*   idx_id = (const int*)d_in[2];
    float*       out    = (float*)d_out;

    addshift_sw_kernel<<<dim3(BATCH * C_OUT_N), dim3(NTHREADS),
                         LDS_HALVES * 2, stream>>>(x, pad_hv, idx_id, out);
}

// Round 15
// 106.857 us; speedup vs baseline: 1.0387x; 1.0387x over previous
//
#include <hip/hip_runtime.h>

// Problem constants (fixed by the reference)
#define BATCH   32
#define C_OUT_N 128
#define NK      5
#define C_IN_N  (NK * C_OUT_N)   // 640
#define HIN     58
#define WIN     58
#define HOUT    56
#define WOUT    56
#define NPIX    (HOUT * WOUT)                       // 3136
#define NTILE   (HOUT * (WOUT / 8))                 // 392 8-px tiles
#define OUT_PLANE ((size_t)BATCH * C_OUT_N * NPIX)  // 12,845,056

// Shift set fixed: REAL_PAD[t] = 4 - 3*t -> {4,1,-2,-5,-8}
// LDS tile: f16 [NK*HIN][70]; x col c at idx 7+c; zeros at idx 0..6, 65..69.
// Window for 8-px tile (h,w0): idx (h+1)*70 + w0 + [0..19]; px i tap t reads
// window col i + 12 - 3t. All reads are b32 f16-pairs (stride 70 = 35 dwords,
// odd -> rows spread across all 32 banks; R10-measured best structure).
// R15 change vs R10: ALL loads (window + v-taps) issue unconditionally at the
// top of each k-iteration; weight-skip branches guard only FMA clusters.
// LDS = 290*70*2 = 40,600 B -> 4 blocks/CU; 512 threads -> ~32 waves/CU.
#define NTHREADS   512
#define LDS_STRIDE 70                        // f16 elements
#define LDS_ROWS   (NK * HIN)                // 290
#define LDS_HALVES (LDS_ROWS * LDS_STRIDE)   // 20,300 -> 40,600 B
#define CH_STRIDE  (HIN * LDS_STRIDE)        // 4060
#define NV4        (NK * HIN * WIN / 4)      // 4205 float4s per (b,co) chunk

typedef _Float16 h2 __attribute__((ext_vector_type(2)));

static __device__ __forceinline__ unsigned int h2u(h2 v) {
    unsigned int r; __builtin_memcpy(&r, &v, 4); return r;
}
static __device__ __forceinline__ h2 uh2(unsigned int u) {
    h2 r; __builtin_memcpy(&r, &u, 4); return r;
}
// shifted-by-one-column f16 pair via v_alignbit_b32
static __device__ __forceinline__ h2 algn(h2 lo, h2 hi) {
    return uh2(__builtin_amdgcn_alignbit(h2u(hi), h2u(lo), 16));
}
// packed f32x2 -> f16x2 (round-toward-zero), bit-cast to our h2 type
static __device__ __forceinline__ h2 pkrtz(float a, float b) {
    auto t = __builtin_amdgcn_cvt_pkrtz(a, b);   // __fp16 ext_vector(2)
    h2 r; __builtin_memcpy(&r, &t, 4); return r;
}
static __device__ __forceinline__ float uni(float v) {   // force SGPR (block-uniform)
    return __uint_as_float(__builtin_amdgcn_readfirstlane(__float_as_uint(v)));
}

__global__ __launch_bounds__(NTHREADS, 8) void addshift_hoist_kernel(
    const float* __restrict__ x,          // (B, C_IN, 58, 58)
    const int*   __restrict__ pad_hv,     // (C_IN, 8): [0..3]=h shifts, [4..7]=v shifts
    const int*   __restrict__ idx_id,     // (C_OUT, 4), values in [co*5, co*5+5)
    float*       __restrict__ out)        // out_h | out_v | out_id concatenated
{
    extern __shared__ _Float16 lds[];

    const int bc  = blockIdx.x;           // b * C_OUT + co
    const int b   = bc / C_OUT_N;
    const int co  = bc - b * C_OUT_N;
    const int tid = threadIdx.x;

    // ---- zero the column margins (12 per row: 0..6 and 65..69)
    for (int i = tid; i < LDS_ROWS * 12; i += NTHREADS) {
        int j = i / 12;
        int m = i - j * 12;
        int c = (m < 7) ? m : (58 + m);
        lds[j * LDS_STRIDE + c] = (_Float16)0.f;
    }

    // ---- stage 5-channel chunk: float4 global loads -> f16 LDS
    // base = r*70 + 7 + c is ODD (c even) -> write [b16][b32 pair][b16]
    const float* xbase = x + (size_t)(b * C_IN_N + co * NK) * (HIN * WIN);
    for (int i = tid; i < NV4; i += NTHREADS) {
        int g = 4 * i;
        float4 v = *(const float4*)(xbase + g);
        int r = g / 58;                   // const division -> magic mul
        int c = g - r * 58;               // even, 0..56
        _Float16* dst = &lds[r * LDS_STRIDE + 7 + c];
        if (c <= 54) {
            dst[0] = (_Float16)v.x;
            *(h2*)(dst + 1) = pkrtz(v.y, v.z);   // even idx, b32 write
            dst[3] = (_Float16)v.w;
        } else {                          // c == 56: last 2 floats wrap to next row
            dst[0] = (_Float16)v.x;
            dst[1] = (_Float16)v.y;
            _Float16* d2 = &lds[(r + 1) * LDS_STRIDE + 7];
            d2[0] = (_Float16)v.z;
            d2[1] = (_Float16)v.w;
        }
    }

    // ---- block-uniform shift multiplicities -> SGPR floats (R10 verbatim)
    float mhf[NK][5], mvf[NK][5], cntf[NK];
    #pragma unroll
    for (int k = 0; k < NK; ++k) {
        #pragma unroll
        for (int t = 0; t < 5; ++t) { mhf[k][t] = 0.f; mvf[k][t] = 0.f; }
        cntf[k] = 0.f;
        #pragma unroll
        for (int g = 0; g < 4; ++g) {
            int sh_v = pad_hv[(co * NK + k) * 8 + g];       // in {4,1,-2,-5,-8}
            int th   = (4 - sh_v) / 3;                      // slot 0..4
            int sv_v = pad_hv[(co * NK + k) * 8 + 4 + g];
            int tv   = (4 - sv_v) / 3;
            #pragma unroll
            for (int t = 0; t < 5; ++t) {
                mhf[k][t] += (th == t) ? 1.f : 0.f;
                mvf[k][t] += (tv == t) ? 1.f : 0.f;
            }
        }
    }
    #pragma unroll
    for (int g = 0; g < 4; ++g) {
        int c = idx_id[co * 4 + g] - co * NK;               // 0..4
        #pragma unroll
        for (int k = 0; k < NK; ++k) cntf[k] += (c == k) ? 1.f : 0.f;
    }
    #pragma unroll
    for (int k = 0; k < NK; ++k) {
        cntf[k] = uni(cntf[k]);
        #pragma unroll
        for (int t = 0; t < 5; ++t) { mhf[k][t] = uni(mhf[k][t]); mvf[k][t] = uni(mvf[k][t]); }
    }

    __syncthreads();

    // ---- compute: one 8-px tile per thread; hoisted loads + branchy FMA
    const int q = tid;
    if (q < NTILE) {
        const int h  = q / 7;
        const int w0 = 8 * (q - h * 7);

        // v-tap rows: clamp address in-bounds; invalid taps get weight 0 later
        int  voff[5];
        bool okv[5];
        #pragma unroll
        for (int t = 0; t < 5; ++t) {
            int rr = h + 5 - 3 * t;       // h+1+(4-3t)
            okv[t] = (unsigned)rr < 58u;
            int rc = rr < 0 ? 0 : (rr > 57 ? 57 : rr);
            voff[t] = rc * LDS_STRIDE + w0 + 8;
        }
        const int rowbase = (h + 1) * LDS_STRIDE + w0;

        h2 sh[4], sv[4], si[4];
        #pragma unroll
        for (int m = 0; m < 4; ++m) {
            sh[m] = h2{(_Float16)0.f, (_Float16)0.f};
            sv[m] = sh[m]; si[m] = sh[m];
        }

        #pragma unroll
        for (int k = 0; k < NK; ++k) {
            const _Float16* chp  = lds + k * CH_STRIDE;
            const _Float16* rowp = chp + rowbase;

            // ---- ALL loads issue here, unconditionally (30 x ds_read_b32) ----
            h2 H[10];
            #pragma unroll
            for (int m = 0; m < 10; ++m) H[m] = *(const h2*)(rowp + 2 * m);

            h2 V[5][4];
            #pragma unroll
            for (int t = 0; t < 5; ++t) {
                const _Float16* vp = chp + voff[t];
                #pragma unroll
                for (int m = 0; m < 4; ++m) V[t][m] = *(const h2*)(vp + 2 * m);
            }

            // ---- out_h: uniform skip of zero-weight taps (register-only work)
            #pragma unroll
            for (int t = 0; t < 5; ++t) {
                float wg = mhf[k][t];
                if (wg != 0.f) {
                    _Float16 wh = (_Float16)wg;
                    h2 w2 = h2{wh, wh};
                    int j = 12 - 3 * t;
                    if ((j & 1) == 0) {
                        int m0 = j >> 1;
                        #pragma unroll
                        for (int m = 0; m < 4; ++m) sh[m] += w2 * H[m0 + m];
                    } else {
                        int m0 = (j - 1) >> 1;
                        #pragma unroll
                        for (int m = 0; m < 4; ++m)
                            sh[m] += w2 * algn(H[m0 + m], H[m0 + m + 1]);
                    }
                }
            }

            // ---- out_id: center cols 8..15 = H[4..7]
            float ck = cntf[k];
            if (ck != 0.f) {
                _Float16 ch16 = (_Float16)ck;
                h2 c2 = h2{ch16, ch16};
                #pragma unroll
                for (int m = 0; m < 4; ++m) si[m] += c2 * H[4 + m];
            }

            // ---- out_v: FMA-only clusters; weight carries the OOB mask
            #pragma unroll
            for (int t = 0; t < 5; ++t) {
                float wv = mvf[k][t];
                if (wv != 0.f) {
                    float wm = okv[t] ? wv : 0.f;
                    _Float16 wh = (_Float16)wm;
                    h2 w2 = h2{wh, wh};
                    #pragma unroll
                    for (int m = 0; m < 4; ++m) sv[m] += w2 * V[t][m];
                }
            }
        }

        size_t o = (size_t)bc * NPIX + h * WOUT + w0;
        *(float4*)(out + o) =
            make_float4((float)sh[0].x, (float)sh[0].y, (float)sh[1].x, (float)sh[1].y);
        *(float4*)(out + o + 4) =
            make_float4((float)sh[2].x, (float)sh[2].y, (float)sh[3].x, (float)sh[3].y);
        *(float4*)(out + OUT_PLANE + o) =
            make_float4((float)sv[0].x, (float)sv[0].y, (float)sv[1].x, (float)sv[1].y);
        *(float4*)(out + OUT_PLANE + o + 4) =
            make_float4((float)sv[2].x, (float)sv[2].y, (float)sv[3].x, (float)sv[3].y);
        *(float4*)(out + 2 * OUT_PLANE + o) =
            make_float4((float)si[0].x, (float)si[0].y, (float)si[1].x, (float)si[1].y);
        *(float4*)(out + 2 * OUT_PLANE + o + 4) =
            make_float4((float)si[2].x, (float)si[2].y, (float)si[3].x, (float)si[3].y);
    }
}

extern "C" void kernel_launch(void* const* d_in, const int* in_sizes, int n_in,
                              void* d_out, int out_size, void* d_ws, size_t ws_size,
                              hipStream_t stream) {
    const float* x      = (const float*)d_in[0];
    const int*   pad_hv = (const int*)d_in[1];
    const int*   idx_id = (const int*)d_in[2];
    float*       out    = (float*)d_out;

    addshift_hoist_kernel<<<dim3(BATCH * C_OUT_N), dim3(NTHREADS),
                            LDS_HALVES * 2, stream>>>(x, pad_hv, idx_id, out);
}